// Round 7
// baseline (1402.384 us; speedup 1.0000x reference)
//
#include <hip/hip_runtime.h>
#include <math.h>

#define SD 7
#define HID 64
#define NITER 10

typedef float f16s __attribute__((ext_vector_type(16)));
typedef float f8s  __attribute__((ext_vector_type(8)));

#define REP4(M)  M(0) M(1) M(2) M(3)
#define REP7(M)  M(0) M(1) M(2) M(3) M(4) M(5) M(6)
#define REP15(M) M(1) M(2) M(3) M(4) M(5) M(6) M(7) M(8) M(9) M(10) M(11) M(12) M(13) M(14) M(15)
#define REP16(M) M(0) M(1) M(2) M(3) M(4) M(5) M(6) M(7) M(8) M(9) M(10) M(11) M(12) M(13) M(14) M(15)
#define AP16(M, ...) M(0, __VA_ARGS__) M(1, __VA_ARGS__) M(2, __VA_ARGS__) M(3, __VA_ARGS__) \
    M(4, __VA_ARGS__) M(5, __VA_ARGS__) M(6, __VA_ARGS__) M(7, __VA_ARGS__) \
    M(8, __VA_ARGS__) M(9, __VA_ARGS__) M(10, __VA_ARGS__) M(11, __VA_ARGS__) \
    M(12, __VA_ARGS__) M(13, __VA_ARGS__) M(14, __VA_ARGS__) M(15, __VA_ARGS__)

// 64 uniform floats -> SGPRs via scalar cache. volatile => never hoisted/CSE'd.
#define SLOAD4(d0, d1, d2, d3, p, o0, o1, o2, o3) \
    asm volatile("s_load_dwordx16 %0, %4, %5\n\t" \
                 "s_load_dwordx16 %1, %4, %6\n\t" \
                 "s_load_dwordx16 %2, %4, %7\n\t" \
                 "s_load_dwordx16 %3, %4, %8\n\t" \
                 "s_waitcnt lgkmcnt(0)" \
                 : "=&s"(d0), "=&s"(d1), "=&s"(d2), "=&s"(d3) \
                 : "s"(p), "i"(o0), "i"(o1), "i"(o2), "i"(o3));

#define SLOAD2P(d0, d1, pa, pb, oa, ob_) \
    asm volatile("s_load_dwordx16 %0, %2, %4\n\t" \
                 "s_load_dwordx16 %1, %3, %5\n\t" \
                 "s_waitcnt lgkmcnt(0)" \
                 : "=&s"(d0), "=&s"(d1) \
                 : "s"(pa), "s"(pb), "i"(oa), "i"(ob_));

#define SLOADX8(d0, p) \
    asm volatile("s_load_dwordx8 %0, %1, 0\n\t" \
                 "s_waitcnt lgkmcnt(0)" \
                 : "=&s"(d0) : "s"(p));

// one fma row element: arr[base+e] = fma(m, W[e], arr[base+e])
#define FMAE(e, arr, base, m, W) (arr)[(base)+(e)] = fmaf((m), (W)[(e)], (arr)[(base)+(e)]);
#define FMAROW(arr, m, wa, wb, wc, wd) \
    AP16(FMAE, arr, 0,  m, wa) AP16(FMAE, arr, 16, m, wb) \
    AP16(FMAE, arr, 32, m, wc) AP16(FMAE, arr, 48, m, wd)

__global__ __launch_bounds__(256) __attribute__((amdgpu_waves_per_eu(2, 2)))
void strange_loop_kernel(const float* __restrict__ s7,
                         const float* __restrict__ w0,
                         const float* __restrict__ b0,
                         const float* __restrict__ lns,
                         const float* __restrict__ lnb,
                         const float* __restrict__ ow,
                         const float* __restrict__ ob,
                         float* __restrict__ out_mu,
                         float* __restrict__ out_cv,
                         int Bn)
{
    int row = blockIdx.x * blockDim.x + threadIdx.x;
    if (row >= Bn) row = Bn - 1;   // clamp: uniform control flow, dup write benign

    float s[SD];
#define LD_S(k) s[k] = s7[(size_t)row * SD + (k)];
    REP7(LD_S)

    // ---- iteration-invariant: Be[j] = b0[j] + sum_k s[k]*W0[7+k][j] ----
    float Be[HID];
    {
        f16s ba, bb, bc, bd;
        SLOAD4(ba, bb, bc, bd, b0, 0, 64, 128, 192)
#define B0E(e, base, W) Be[(base)+(e)] = (W)[(e)];
        AP16(B0E, 0, ba) AP16(B0E, 16, bb) AP16(B0E, 32, bc) AP16(B0E, 48, bd)
    }
#define BIK(k) { f16s wa, wb, wc, wd; \
    SLOAD4(wa, wb, wc, wd, w0, (7+(k))*256, (7+(k))*256+64, (7+(k))*256+128, (7+(k))*256+192) \
    const float sk = s[k]; \
    FMAROW(Be, sk, wa, wb, wc, wd) }
    REP7(BIK)

    f8s obv;
    SLOADX8(obv, ob)

    float mu[SD];
#define INITMU(i) mu[i] = 0.37796447300922720f;   // 1/sqrt(7)
    REP7(INITMU)
    float conv = 0.0f;

#pragma unroll 1
    for (int it = 0; it < NITER; ++it) {
        // ---- fc0: xe = Be + sum_k mu[k]*W0[k][.] ----
        float xe[HID];
#define CPE(e, base) xe[(base)+(e)] = Be[(base)+(e)];
        AP16(CPE, 0) AP16(CPE, 16) AP16(CPE, 32) AP16(CPE, 48)
#define FC0K(k) { f16s wa, wb, wc, wd; \
        SLOAD4(wa, wb, wc, wd, w0, (k)*256, (k)*256+64, (k)*256+128, (k)*256+192) \
        const float mk = mu[k]; \
        FMAROW(xe, mk, wa, wb, wc, wd) }
        REP7(FC0K)

        // ---- LayerNorm (two-pass, striped partials: same order as passing kernel) ----
        float p0 = xe[0], p1 = xe[1], p2 = xe[2], p3 = xe[3];
#define SACE(q) p0 += xe[4*(q)+0]; p1 += xe[4*(q)+1]; p2 += xe[4*(q)+2]; p3 += xe[4*(q)+3];
        REP15(SACE)
        float mean = ((p0 + p1) + (p2 + p3)) * (1.0f / HID);

        float v0 = 0.f, v1 = 0.f, v2 = 0.f, v3 = 0.f;
#define VACE(q) { float a0 = xe[4*(q)+0] - mean, a1 = xe[4*(q)+1] - mean; \
        float a2 = xe[4*(q)+2] - mean, a3 = xe[4*(q)+3] - mean; \
        v0 = fmaf(a0, a0, v0); v1 = fmaf(a1, a1, v1); \
        v2 = fmaf(a2, a2, v2); v3 = fmaf(a3, a3, v3); \
        xe[4*(q)+0] = a0; xe[4*(q)+1] = a1; xe[4*(q)+2] = a2; xe[4*(q)+3] = a3; }
        REP16(VACE)
        float var  = ((v0 + v1) + (v2 + v3)) * (1.0f / HID);
        float rstd = 1.0f / sqrtf(var + 1e-6f);

        // ---- scale/shift + GELU (formula identical to passing kernel) ----
#define GELE(e, base, LS, LB) { float g = fmaf(xe[(base)+(e)] * rstd, (LS)[(e)], (LB)[(e)]); \
        float g2 = g * g; float g3 = g2 * g; \
        float z  = -1.5957691216057308f * fmaf(0.044715f, g3, g); \
        float ex = __expf(z); \
        xe[(base)+(e)] = __fdividef(g, 1.0f + ex); }
#define GELG(h) { f16s ls, lb2; \
        SLOAD2P(ls, lb2, lns, lnb, (h)*64, (h)*64) \
        AP16(GELE, 16*(h), ls, lb2) }
        REP4(GELG)

        // ---- out matmul [1x64]x[64x7]: flat-ascending == j-ascending per i ----
        float u[SD];
#define IU(i) u[i] = obv[i];
        REP7(IU)
#define OUTE(e, m, W) u[(16*(m)+(e))%7] = fmaf(xe[(16*(m)+(e))/7], (W)[(e)], u[(16*(m)+(e))%7]);
#define OUTG(g) { f16s a0, a1, a2, a3; \
        SLOAD4(a0, a1, a2, a3, ow, (g)*256, (g)*256+64, (g)*256+128, (g)*256+192) \
        AP16(OUTE, 4*(g)+0, a0) AP16(OUTE, 4*(g)+1, a1) \
        AP16(OUTE, 4*(g)+2, a2) AP16(OUTE, 4*(g)+3, a3) }
        REP7(OUTG)

        // ---- L2 normalize ----
        float ss = 0.f;
#define SSQ(i) ss = fmaf(u[i], u[i], ss);
        REP7(SSQ)
        float inv = __fdividef(1.0f, sqrtf(ss) + 1e-8f);

        // ---- damped update + convergence ----
        float dd = 0.f;
#define UPD(i) { float un = u[i] * inv; float mn = 0.5f * mu[i] + 0.5f * un; \
        float d = mn - mu[i]; dd = fmaf(d, d, dd); mu[i] = mn; }
        REP7(UPD)
        if (sqrtf(dd) < 1e-4f) conv = 1.0f;
    }

#define ST(i) out_mu[(size_t)row * SD + (i)] = mu[i];
    REP7(ST)
    out_cv[row] = conv;
}

extern "C" void kernel_launch(void* const* d_in, const int* in_sizes, int n_in,
                              void* d_out, int out_size, void* d_ws, size_t ws_size,
                              hipStream_t stream) {
    const float* s7  = (const float*)d_in[0];
    const float* w0  = (const float*)d_in[1];
    const float* b0  = (const float*)d_in[2];
    const float* lns = (const float*)d_in[3];
    const float* lnb = (const float*)d_in[4];
    const float* ow  = (const float*)d_in[5];
    const float* ob  = (const float*)d_in[6];
    const int Bn = in_sizes[0] / SD;

    float* out_mu = (float*)d_out;
    float* out_cv = out_mu + (size_t)Bn * SD;

    const int block = 256;
    const int grid  = (Bn + block - 1) / block;
    hipLaunchKernelGGL(strange_loop_kernel, dim3(grid), dim3(block), 0, stream,
                       s7, w0, b0, lns, lnb, ow, ob, out_mu, out_cv, Bn);
}

// Round 8
// 1267.488 us; speedup vs baseline: 1.1064x; 1.1064x over previous
//
#include <hip/hip_runtime.h>
#include <math.h>

#define SD 7
#define HID 64
#define NITER 10

typedef float f16s __attribute__((ext_vector_type(16)));
typedef float f8s  __attribute__((ext_vector_type(8)));
typedef float f2   __attribute__((ext_vector_type(2)));

#define REP4(M)  M(0) M(1) M(2) M(3)
#define REP7(M)  M(0) M(1) M(2) M(3) M(4) M(5) M(6)
#define REP15(M) M(1) M(2) M(3) M(4) M(5) M(6) M(7) M(8) M(9) M(10) M(11) M(12) M(13) M(14) M(15)
#define REP16(M) M(0) M(1) M(2) M(3) M(4) M(5) M(6) M(7) M(8) M(9) M(10) M(11) M(12) M(13) M(14) M(15)
#define AP8(M, ...) M(0, __VA_ARGS__) M(1, __VA_ARGS__) M(2, __VA_ARGS__) M(3, __VA_ARGS__) \
    M(4, __VA_ARGS__) M(5, __VA_ARGS__) M(6, __VA_ARGS__) M(7, __VA_ARGS__)
#define AP16(M, ...) M(0, __VA_ARGS__) M(1, __VA_ARGS__) M(2, __VA_ARGS__) M(3, __VA_ARGS__) \
    M(4, __VA_ARGS__) M(5, __VA_ARGS__) M(6, __VA_ARGS__) M(7, __VA_ARGS__) \
    M(8, __VA_ARGS__) M(9, __VA_ARGS__) M(10, __VA_ARGS__) M(11, __VA_ARGS__) \
    M(12, __VA_ARGS__) M(13, __VA_ARGS__) M(14, __VA_ARGS__) M(15, __VA_ARGS__)

// 64 uniform floats -> SGPRs via scalar cache. volatile => never hoisted/CSE'd.
#define SLOAD4(d0, d1, d2, d3, p, o0, o1, o2, o3) \
    asm volatile("s_load_dwordx16 %0, %4, %5\n\t" \
                 "s_load_dwordx16 %1, %4, %6\n\t" \
                 "s_load_dwordx16 %2, %4, %7\n\t" \
                 "s_load_dwordx16 %3, %4, %8\n\t" \
                 "s_waitcnt lgkmcnt(0)" \
                 : "=&s"(d0), "=&s"(d1), "=&s"(d2), "=&s"(d3) \
                 : "s"(p), "i"(o0), "i"(o1), "i"(o2), "i"(o3));

#define SLOAD2P(d0, d1, pa, pb, oa, ob_) \
    asm volatile("s_load_dwordx16 %0, %2, %4\n\t" \
                 "s_load_dwordx16 %1, %3, %5\n\t" \
                 "s_waitcnt lgkmcnt(0)" \
                 : "=&s"(d0), "=&s"(d1) \
                 : "s"(pa), "s"(pb), "i"(oa), "i"(ob_));

#define SLOADX8(d0, p) \
    asm volatile("s_load_dwordx8 %0, %1, 0\n\t" \
                 "s_waitcnt lgkmcnt(0)" \
                 : "=&s"(d0) : "s"(p));

// SGPR weight pair (even-aligned subreg of a dwordx16 group)
#define PAIR(W, e) ((f2){(W)[2*(e)], (W)[2*(e)+1]})

// packed fma: acc = w*m + acc  (per half; identical rounding to v_fma_f32)
#define PKFMA_ACC(acc, w2v, m2v) \
    asm("v_pk_fma_f32 %0, %1, %2, %0" : "+v"(acc) : "s"(w2v), "v"(m2v));
// packed fma into fresh dst: dst = w*m + add
#define PKFMA_NEW(dst, w2v, m2v, add2) \
    asm("v_pk_fma_f32 %0, %1, %2, %3" : "=v"(dst) : "s"(w2v), "v"(m2v), "v"(add2));

// one packed row chunk: arr[base+e] += W.pair(e) * m2
#define PKROW_E(e, arr, base, m2v, W) PKFMA_ACC((arr)[(base)+(e)], PAIR(W, e), m2v)
#define PKROW(arr, m2v, wa, wb, wc, wd) \
    AP8(PKROW_E, arr, 0,  m2v, wa) AP8(PKROW_E, arr, 8,  m2v, wb) \
    AP8(PKROW_E, arr, 16, m2v, wc) AP8(PKROW_E, arr, 24, m2v, wd)

__global__ __launch_bounds__(256) __attribute__((amdgpu_waves_per_eu(1, 1)))
void strange_loop_kernel(const float* __restrict__ s7,
                         const float* __restrict__ w0,
                         const float* __restrict__ b0,
                         const float* __restrict__ lns,
                         const float* __restrict__ lnb,
                         const float* __restrict__ ow,
                         const float* __restrict__ ob,
                         float* __restrict__ out_mu,
                         float* __restrict__ out_cv,
                         int Bn)
{
    int row = blockIdx.x * blockDim.x + threadIdx.x;
    if (row >= Bn) row = Bn - 1;   // clamp: uniform control flow, dup write benign

    float s[SD];
#define LD_S(k) s[k] = s7[(size_t)row * SD + (k)];
    REP7(LD_S)

    // ---- iteration-invariant: Be2 = b0 + sum_k s[k]*W0[7+k][.] (packed pairs) ----
    f2 Be2[32];
    {
        f16s ba, bb, bc, bd;
        SLOAD4(ba, bb, bc, bd, b0, 0, 64, 128, 192)
#define B0P(e, base, W) Be2[(base)+(e)] = PAIR(W, e);
        AP8(B0P, 0, ba) AP8(B0P, 8, bb) AP8(B0P, 16, bc) AP8(B0P, 24, bd)
    }
#define BIK(k) { f16s wa, wb, wc, wd; \
    SLOAD4(wa, wb, wc, wd, w0, (7+(k))*256, (7+(k))*256+64, (7+(k))*256+128, (7+(k))*256+192) \
    f2 m2 = {s[k], s[k]}; \
    PKROW(Be2, m2, wa, wb, wc, wd) }
    REP7(BIK)

    f8s obv;
    SLOADX8(obv, ob)

    float mu[SD];
#define INITMU(i) mu[i] = 0.37796447300922720f;   // 1/sqrt(7)
    REP7(INITMU)
    float conv = 0.0f;

#pragma unroll 1
    for (int it = 0; it < NITER; ++it) {
        // ---- fc0: xe2 = Be2 + sum_k mu[k]*W0[k][.] ; k=0 writes fresh (no copy) ----
        f2 xe2[32];
        { f16s wa, wb, wc, wd;
          SLOAD4(wa, wb, wc, wd, w0, 0, 64, 128, 192)
          f2 m2 = {mu[0], mu[0]};
#define FC00_E(e, base, W) PKFMA_NEW(xe2[(base)+(e)], PAIR(W, e), m2, Be2[(base)+(e)])
          AP8(FC00_E, 0, wa) AP8(FC00_E, 8, wb) AP8(FC00_E, 16, wc) AP8(FC00_E, 24, wd)
        }
#define FC0K(k) { f16s wa, wb, wc, wd; \
        SLOAD4(wa, wb, wc, wd, w0, (k)*256, (k)*256+64, (k)*256+128, (k)*256+192) \
        f2 m2 = {mu[k], mu[k]}; \
        PKROW(xe2, m2, wa, wb, wc, wd) }
        FC0K(1) FC0K(2) FC0K(3) FC0K(4) FC0K(5) FC0K(6)

        // ---- LayerNorm (two-pass; striped partials, exact same chains) ----
        f2 P01 = xe2[0], P23 = xe2[1];
#define SACE(q) P01 += xe2[2*(q)]; P23 += xe2[2*(q)+1];
        REP15(SACE)
        float mean = ((P01.x + P01.y) + (P23.x + P23.y)) * (1.0f / HID);

        f2 V01 = {0.f, 0.f}, V23 = {0.f, 0.f};
        {
            f2 mn2 = {mean, mean};
#define VACE(q) { f2 a0 = xe2[2*(q)] - mn2; f2 a1 = xe2[2*(q)+1] - mn2; \
            V01 = __builtin_elementwise_fma(a0, a0, V01); \
            V23 = __builtin_elementwise_fma(a1, a1, V23); \
            xe2[2*(q)] = a0; xe2[2*(q)+1] = a1; }
            REP16(VACE)
        }
        float var  = ((V01.x + V01.y) + (V23.x + V23.y)) * (1.0f / HID);
        float rstd = 1.0f / sqrtf(var + 1e-6f);

        // ---- scale/shift + GELU (scalar, formula identical to passing kernel) ----
#define GELE(e, base8, LS, LB) { \
        float xv = ((e)%2==0) ? xe2[(base8)+(e)/2].x : xe2[(base8)+(e)/2].y; \
        float g = fmaf(xv * rstd, (LS)[(e)], (LB)[(e)]); \
        float g2 = g * g; float g3 = g2 * g; \
        float z  = -1.5957691216057308f * fmaf(0.044715f, g3, g); \
        float ex = __expf(z); \
        float r = __fdividef(g, 1.0f + ex); \
        if ((e)%2==0) xe2[(base8)+(e)/2].x = r; else xe2[(base8)+(e)/2].y = r; }
#define GELG(h) { f16s ls, lb2; \
        SLOAD2P(ls, lb2, lns, lnb, (h)*64, (h)*64) \
        AP16(GELE, 8*(h), ls, lb2) }
        REP4(GELG)

        // ---- out matmul [1x64]x[64x7]: flat-ascending == j-ascending per i ----
        float u[SD];
#define IU(i) u[i] = obv[i];
        REP7(IU)
#define XE(f) (((f)%2==0) ? xe2[(f)/2].x : xe2[(f)/2].y)
#define OUTE(e, m, W) u[(16*(m)+(e))%7] = fmaf(XE((16*(m)+(e))/7), (W)[(e)], u[(16*(m)+(e))%7]);
#define OUTG(g) { f16s a0, a1, a2, a3; \
        SLOAD4(a0, a1, a2, a3, ow, (g)*256, (g)*256+64, (g)*256+128, (g)*256+192) \
        AP16(OUTE, 4*(g)+0, a0) AP16(OUTE, 4*(g)+1, a1) \
        AP16(OUTE, 4*(g)+2, a2) AP16(OUTE, 4*(g)+3, a3) }
        REP7(OUTG)

        // ---- L2 normalize ----
        float ss = 0.f;
#define SSQ(i) ss = fmaf(u[i], u[i], ss);
        REP7(SSQ)
        float inv = __fdividef(1.0f, sqrtf(ss) + 1e-8f);

        // ---- damped update + convergence ----
        float dd = 0.f;
#define UPD(i) { float un = u[i] * inv; float mn = 0.5f * mu[i] + 0.5f * un; \
        float d = mn - mu[i]; dd = fmaf(d, d, dd); mu[i] = mn; }
        REP7(UPD)
        if (sqrtf(dd) < 1e-4f) conv = 1.0f;
    }

#define ST(i) out_mu[(size_t)row * SD + (i)] = mu[i];
    REP7(ST)
    out_cv[row] = conv;
}

extern "C" void kernel_launch(void* const* d_in, const int* in_sizes, int n_in,
                              void* d_out, int out_size, void* d_ws, size_t ws_size,
                              hipStream_t stream) {
    const float* s7  = (const float*)d_in[0];
    const float* w0  = (const float*)d_in[1];
    const float* b0  = (const float*)d_in[2];
    const float* lns = (const float*)d_in[3];
    const float* lnb = (const float*)d_in[4];
    const float* ow  = (const float*)d_in[5];
    const float* ob  = (const float*)d_in[6];
    const int Bn = in_sizes[0] / SD;

    float* out_mu = (float*)d_out;
    float* out_cv = out_mu + (size_t)Bn * SD;

    const int block = 256;
    const int grid  = (Bn + block - 1) / block;
    hipLaunchKernelGGL(strange_loop_kernel, dim3(grid), dim3(block), 0, stream,
                       s7, w0, b0, lns, lnb, ow, ob, out_mu, out_cv, Bn);
}

// Round 9
// 1067.556 us; speedup vs baseline: 1.3136x; 1.1873x over previous
//
#include <hip/hip_runtime.h>
#include <math.h>

#define SD 7
#define HID 64
#define NITER 10

typedef float f16s __attribute__((ext_vector_type(16)));
typedef float f8s  __attribute__((ext_vector_type(8)));

#define REP4(M)  M(0) M(1) M(2) M(3)
#define REP7(M)  M(0) M(1) M(2) M(3) M(4) M(5) M(6)
#define REP15(M) M(1) M(2) M(3) M(4) M(5) M(6) M(7) M(8) M(9) M(10) M(11) M(12) M(13) M(14) M(15)
#define REP16(M) M(0) M(1) M(2) M(3) M(4) M(5) M(6) M(7) M(8) M(9) M(10) M(11) M(12) M(13) M(14) M(15)
#define REP28(M) M(0) M(1) M(2) M(3) M(4) M(5) M(6) M(7) M(8) M(9) M(10) M(11) M(12) M(13) \
                 M(14) M(15) M(16) M(17) M(18) M(19) M(20) M(21) M(22) M(23) M(24) M(25) M(26) M(27)
#define AP16(M, ...) M(0, __VA_ARGS__) M(1, __VA_ARGS__) M(2, __VA_ARGS__) M(3, __VA_ARGS__) \
    M(4, __VA_ARGS__) M(5, __VA_ARGS__) M(6, __VA_ARGS__) M(7, __VA_ARGS__) \
    M(8, __VA_ARGS__) M(9, __VA_ARGS__) M(10, __VA_ARGS__) M(11, __VA_ARGS__) \
    M(12, __VA_ARGS__) M(13, __VA_ARGS__) M(14, __VA_ARGS__) M(15, __VA_ARGS__)

// one x16 group + wait: 16 uniform floats -> SGPRs. volatile => never hoisted.
// Small live range: consumed immediately by the 16 FMAs that follow.
#define SLD16(d, obytes, p) \
    asm volatile("s_load_dwordx16 %0, %1, %2\n\t" \
                 "s_waitcnt lgkmcnt(0)" \
                 : "=&s"(d) : "s"(p), "i"(obytes));

#define SLOAD2P(d0, d1, pa, pb, oa, ob_) \
    asm volatile("s_load_dwordx16 %0, %2, %4\n\t" \
                 "s_load_dwordx16 %1, %3, %5\n\t" \
                 "s_waitcnt lgkmcnt(0)" \
                 : "=&s"(d0), "=&s"(d1) \
                 : "s"(pa), "s"(pb), "i"(oa), "i"(ob_));

#define SLOADX8(d0, p) \
    asm volatile("s_load_dwordx8 %0, %1, 0\n\t" \
                 "s_waitcnt lgkmcnt(0)" \
                 : "=&s"(d0) : "s"(p));

__global__ __launch_bounds__(256) __attribute__((amdgpu_waves_per_eu(2)))
void strange_loop_kernel(const float* __restrict__ s7,
                         const float* __restrict__ w0,
                         const float* __restrict__ b0,
                         const float* __restrict__ lns,
                         const float* __restrict__ lnb,
                         const float* __restrict__ ow,
                         const float* __restrict__ ob,
                         float* __restrict__ out_mu,
                         float* __restrict__ out_cv,
                         int Bn)
{
    int row = blockIdx.x * blockDim.x + threadIdx.x;
    if (row >= Bn) row = Bn - 1;   // clamp: uniform control flow, dup write benign

    float s[SD];
#define LD_S(k) s[k] = s7[(size_t)row * SD + (k)];
    REP7(LD_S)

    // ---- iteration-invariant Be = b0 + sum_k s[k]*W0[7+k][.], built CHUNKED ----
    // per-element op order identical to round-4 (b0, then k=0..6 ascending)
    float Be[HID];
#define B0E2(e, c, W) Be[(c)*16+(e)] = (W)[(e)];
#define BEE(e, c, sk, W) Be[(c)*16+(e)] = fmaf((sk), (W)[(e)], Be[(c)*16+(e)]);
#define BECK(c, k) { f16s w; SLD16(w, (7+(k))*256 + (c)*64, w0) AP16(BEE, c, s[k], w) }
#define BECHUNK(c) { { f16s bb; SLD16(bb, (c)*64, b0) AP16(B0E2, c, bb) } \
    BECK(c, 0) BECK(c, 1) BECK(c, 2) BECK(c, 3) BECK(c, 4) BECK(c, 5) BECK(c, 6) }
    REP4(BECHUNK)

    f8s obv;
    SLOADX8(obv, ob)

    float mu[SD];
#define INITMU(i) mu[i] = 0.37796447300922720f;   // 1/sqrt(7)
    REP7(INITMU)
    float conv = 0.0f;

#pragma unroll 1
    for (int it = 0; it < NITER; ++it) {
        // ---- fc0 CHUNKED (k-inner): chunk stays register-resident across its
        // whole k-sweep; per-element FMA order (k=0..6) identical to round 4 ----
        float xe[HID];
#define CPE2(e, c) xe[(c)*16+(e)] = Be[(c)*16+(e)];
#define FCE(e, c, mk, W) xe[(c)*16+(e)] = fmaf((mk), (W)[(e)], xe[(c)*16+(e)]);
#define FCCK(c, k) { f16s w; SLD16(w, (k)*256 + (c)*64, w0) AP16(FCE, c, mu[k], w) }
#define FCCHUNK(c) { AP16(CPE2, c) \
        FCCK(c, 0) FCCK(c, 1) FCCK(c, 2) FCCK(c, 3) FCCK(c, 4) FCCK(c, 5) FCCK(c, 6) }
        REP4(FCCHUNK)

        // ---- LayerNorm (two-pass, striped partials: same order as round 4) ----
        float p0 = xe[0], p1 = xe[1], p2 = xe[2], p3 = xe[3];
#define SACE(q) p0 += xe[4*(q)+0]; p1 += xe[4*(q)+1]; p2 += xe[4*(q)+2]; p3 += xe[4*(q)+3];
        REP15(SACE)
        float mean = ((p0 + p1) + (p2 + p3)) * (1.0f / HID);

        float v0 = 0.f, v1 = 0.f, v2 = 0.f, v3 = 0.f;
#define VACE(q) { float a0 = xe[4*(q)+0] - mean, a1 = xe[4*(q)+1] - mean; \
        float a2 = xe[4*(q)+2] - mean, a3 = xe[4*(q)+3] - mean; \
        v0 = fmaf(a0, a0, v0); v1 = fmaf(a1, a1, v1); \
        v2 = fmaf(a2, a2, v2); v3 = fmaf(a3, a3, v3); \
        xe[4*(q)+0] = a0; xe[4*(q)+1] = a1; xe[4*(q)+2] = a2; xe[4*(q)+3] = a3; }
        REP16(VACE)
        float var  = ((v0 + v1) + (v2 + v3)) * (1.0f / HID);
        float rstd = 1.0f / sqrtf(var + 1e-6f);

        // ---- scale/shift + GELU (formula identical to passing kernels) ----
#define GELE(e, base, LS, LB) { float g = fmaf(xe[(base)+(e)] * rstd, (LS)[(e)], (LB)[(e)]); \
        float g2 = g * g; float g3 = g2 * g; \
        float z  = -1.5957691216057308f * fmaf(0.044715f, g3, g); \
        float ex = __expf(z); \
        xe[(base)+(e)] = __fdividef(g, 1.0f + ex); }
#define GELG(h) { f16s ls, lb2; \
        SLOAD2P(ls, lb2, lns, lnb, (h)*64, (h)*64) \
        AP16(GELE, 16*(h), ls, lb2) }
        REP4(GELG)

        // ---- out matmul [1x64]x[64x7], 16-weight blocks, flat-ascending order ----
        float u[SD];
#define IU(i) u[i] = obv[i];
        REP7(IU)
#define OUTE(e, m, W) u[(16*(m)+(e))%7] = fmaf(xe[(16*(m)+(e))/7], (W)[(e)], u[(16*(m)+(e))%7]);
#define OUTB(m) { f16s w; SLD16(w, (m)*64, ow) AP16(OUTE, m, w) }
        REP28(OUTB)

        // ---- L2 normalize ----
        float ss = 0.f;
#define SSQ(i) ss = fmaf(u[i], u[i], ss);
        REP7(SSQ)
        float inv = __fdividef(1.0f, sqrtf(ss) + 1e-8f);

        // ---- damped update + convergence ----
        float dd = 0.f;
#define UPD(i) { float un = u[i] * inv; float mn = 0.5f * mu[i] + 0.5f * un; \
        float d = mn - mu[i]; dd = fmaf(d, d, dd); mu[i] = mn; }
        REP7(UPD)
        if (sqrtf(dd) < 1e-4f) conv = 1.0f;
    }

#define ST(i) out_mu[(size_t)row * SD + (i)] = mu[i];
    REP7(ST)
    out_cv[row] = conv;
}

extern "C" void kernel_launch(void* const* d_in, const int* in_sizes, int n_in,
                              void* d_out, int out_size, void* d_ws, size_t ws_size,
                              hipStream_t stream) {
    const float* s7  = (const float*)d_in[0];
    const float* w0  = (const float*)d_in[1];
    const float* b0  = (const float*)d_in[2];
    const float* lns = (const float*)d_in[3];
    const float* lnb = (const float*)d_in[4];
    const float* ow  = (const float*)d_in[5];
    const float* ob  = (const float*)d_in[6];
    const int Bn = in_sizes[0] / SD;

    float* out_mu = (float*)d_out;
    float* out_cv = out_mu + (size_t)Bn * SD;

    const int block = 256;
    const int grid  = (Bn + block - 1) / block;
    hipLaunchKernelGGL(strange_loop_kernel, dim3(grid), dim3(block), 0, stream,
                       s7, w0, b0, lns, lnb, ow, ob, out_mu, out_cv, Bn);
}

// Round 10
// 921.176 us; speedup vs baseline: 1.5224x; 1.1589x over previous
//
#include <hip/hip_runtime.h>
#include <math.h>

#define SD 7
#define HID 64
#define NITER 10

typedef float f4 __attribute__((ext_vector_type(4)));
typedef float f2 __attribute__((ext_vector_type(2)));

// ---- DPP butterfly add over aligned 8-lane groups (pure VALU, no LDS pipe) ----
template<int CTRL>
__device__ __forceinline__ float dpp_add(float v) {
    int t = __builtin_amdgcn_update_dpp(0, __float_as_int(v), CTRL, 0xf, 0xf, true);
    return v + __int_as_float(t);
}
__device__ __forceinline__ float red8(float v) {
    v = dpp_add<0xB1>(v);   // quad_perm [1,0,3,2]  : xor 1
    v = dpp_add<0x4E>(v);   // quad_perm [2,3,0,1]  : xor 2
    v = dpp_add<0x141>(v);  // row_half_mirror      : combine quads within 8
    return v;               // all 8 lanes end with the bit-identical total
}

// ow row chunk read (2 x b128, wait inside block) + accumulate into pu[]
#define OWC0() { f4 wa, wb; \
    asm volatile("ds_read_b128 %0, %2 offset:0\n\t" \
                 "ds_read_b128 %1, %2 offset:16\n\t" \
                 "s_waitcnt lgkmcnt(0)" \
                 : "=&v"(wa), "=&v"(wb) : "v"(aow)); \
    pu[0]=xe[0]*wa.x; pu[1]=xe[0]*wa.y; pu[2]=xe[0]*wa.z; pu[3]=xe[0]*wa.w; \
    pu[4]=xe[0]*wb.x; pu[5]=xe[0]*wb.y; pu[6]=xe[0]*wb.z; }

#define OWC(cc, o0, o1) { f4 wa, wb; \
    asm volatile("ds_read_b128 %0, %2 offset:" o0 "\n\t" \
                 "ds_read_b128 %1, %2 offset:" o1 "\n\t" \
                 "s_waitcnt lgkmcnt(0)" \
                 : "=&v"(wa), "=&v"(wb) : "v"(aow)); \
    pu[0]=fmaf(xe[cc],wa.x,pu[0]); pu[1]=fmaf(xe[cc],wa.y,pu[1]); \
    pu[2]=fmaf(xe[cc],wa.z,pu[2]); pu[3]=fmaf(xe[cc],wa.w,pu[3]); \
    pu[4]=fmaf(xe[cc],wb.x,pu[4]); pu[5]=fmaf(xe[cc],wb.y,pu[5]); \
    pu[6]=fmaf(xe[cc],wb.z,pu[6]); }

// GELU on element c using lp##c = {lns[j], lnb[j]} (formula identical to r4)
#define GELC(c) { float g = fmaf(xe[c] * rstd, lp##c.x, lp##c.y); \
    float g2 = g * g; float g3 = g2 * g; \
    float z  = -1.5957691216057308f * fmaf(0.044715f, g3, g); \
    float ex = __expf(z); \
    xe[c] = __fdividef(g, 1.0f + ex); }

__global__ __launch_bounds__(256) __attribute__((amdgpu_waves_per_eu(3, 4)))
void strange_loop_kernel(const float* __restrict__ s7,
                         const float* __restrict__ w0,
                         const float* __restrict__ b0,
                         const float* __restrict__ lns,
                         const float* __restrict__ lnb,
                         const float* __restrict__ ow,
                         const float* __restrict__ ob,
                         float* __restrict__ out_mu,
                         float* __restrict__ out_cv,
                         int Bn)
{
    __shared__ __align__(16) float owP[HID * 8];  // [64][8], 7 real + 1 pad
    __shared__ float lnp[2 * HID];                // lns[64] | lnb[64]

    const int tid = threadIdx.x;
    for (int idx = tid; idx < HID * SD; idx += 256)
        owP[(idx / SD) * 8 + (idx % SD)] = ow[idx];
    if (tid < HID) { lnp[tid] = lns[tid]; lnp[HID + tid] = lnb[tid]; }
    __syncthreads();

    const int lane = tid & 63;
    const int e    = lane & 7;          // element group: j = e + 8c
    const int g    = lane >> 3;         // row within wave
    const int wave = tid >> 6;
    int row = (blockIdx.x * 4 + wave) * 8 + g;
    if (row >= Bn) row = Bn - 1;        // clamp: duplicate work, consistent values

    // LDS byte addresses (low 32 bits of flat LDS pointer = LDS offset)
    const unsigned aow = (unsigned)(size_t)(&owP[0]) + (unsigned)(e * 32);
    const unsigned aln = (unsigned)(size_t)(&lnp[0]) + (unsigned)(e * 4);

    // ---- one-time loads ----
    float s[SD];
    #pragma unroll
    for (int k = 0; k < SD; ++k) s[k] = s7[(size_t)row * SD + k];

    float wM[SD][8];                    // fc0 mu-half weights, hoisted (56 regs)
    #pragma unroll
    for (int k = 0; k < SD; ++k)
        #pragma unroll
        for (int c = 0; c < 8; ++c) wM[k][c] = w0[k * HID + e + 8 * c];

    float Be[8];                        // b0 + ctx (k ascending, same elem order)
    #pragma unroll
    for (int c = 0; c < 8; ++c) Be[c] = b0[e + 8 * c];
    #pragma unroll
    for (int k = 0; k < SD; ++k) {
        const float sk = s[k];
        #pragma unroll
        for (int c = 0; c < 8; ++c)
            Be[c] = fmaf(sk, w0[(SD + k) * HID + e + 8 * c], Be[c]);
    }

    float obv[SD];
    #pragma unroll
    for (int i = 0; i < SD; ++i) obv[i] = ob[i];

    float mu[SD];
    #pragma unroll
    for (int i = 0; i < SD; ++i) mu[i] = 0.37796447300922720f;  // 1/sqrt(7)
    float conv = 0.0f;

    #pragma unroll 1
    for (int it = 0; it < NITER; ++it) {
        // ---- fc0: xe[c] = Be[c] + sum_k mu[k]*wM[k][c] ----
        float xe[8];
        #pragma unroll
        for (int c = 0; c < 8; ++c) xe[c] = fmaf(mu[0], wM[0][c], Be[c]);
        #pragma unroll
        for (int k = 1; k < SD; ++k)
            #pragma unroll
            for (int c = 0; c < 8; ++c) xe[c] = fmaf(mu[k], wM[k][c], xe[c]);

        // ---- LayerNorm mean (local pairwise + DPP tree) ----
        float t01 = xe[0] + xe[1], t23 = xe[2] + xe[3];
        float t45 = xe[4] + xe[5], t67 = xe[6] + xe[7];
        float mean = red8((t01 + t23) + (t45 + t67)) * (1.0f / HID);

        // ---- variance ----
        float v0 = 0.f, v1 = 0.f;
        #pragma unroll
        for (int c = 0; c < 8; c += 2) {
            float a0 = xe[c] - mean, a1 = xe[c + 1] - mean;
            v0 = fmaf(a0, a0, v0); v1 = fmaf(a1, a1, v1);
            xe[c] = a0; xe[c + 1] = a1;
        }
        float var  = red8(v0 + v1) * (1.0f / HID);
        float rstd = 1.0f / sqrtf(var + 1e-6f);

        // ---- ln params from LDS (volatile batched; wait inside block) ----
        f2 lp0, lp1, lp2, lp3, lp4, lp5, lp6, lp7;
        asm volatile(
            "ds_read2_b32 %0, %8 offset0:0 offset1:64\n\t"
            "ds_read2_b32 %1, %8 offset0:8 offset1:72\n\t"
            "ds_read2_b32 %2, %8 offset0:16 offset1:80\n\t"
            "ds_read2_b32 %3, %8 offset0:24 offset1:88\n\t"
            "ds_read2_b32 %4, %8 offset0:32 offset1:96\n\t"
            "ds_read2_b32 %5, %8 offset0:40 offset1:104\n\t"
            "ds_read2_b32 %6, %8 offset0:48 offset1:112\n\t"
            "ds_read2_b32 %7, %8 offset0:56 offset1:120\n\t"
            "s_waitcnt lgkmcnt(0)"
            : "=&v"(lp0), "=&v"(lp1), "=&v"(lp2), "=&v"(lp3),
              "=&v"(lp4), "=&v"(lp5), "=&v"(lp6), "=&v"(lp7)
            : "v"(aln));

        GELC(0) GELC(1) GELC(2) GELC(3) GELC(4) GELC(5) GELC(6) GELC(7)

        // ---- out matmul partials over my 8 j's, ow rows from LDS ----
        float pu[SD];
        OWC0()
        OWC(1, "256",  "272")
        OWC(2, "512",  "528")
        OWC(3, "768",  "784")
        OWC(4, "1024", "1040")
        OWC(5, "1280", "1296")
        OWC(6, "1536", "1552")
        OWC(7, "1792", "1808")

        // ---- reduce partials across the 8 lanes, add bias ----
        float u[SD];
        #pragma unroll
        for (int i = 0; i < SD; ++i) u[i] = red8(pu[i]) + obv[i];

        // ---- L2 normalize (identical to r4) ----
        float ss = 0.f;
        #pragma unroll
        for (int i = 0; i < SD; ++i) ss = fmaf(u[i], u[i], ss);
        float inv = __fdividef(1.0f, sqrtf(ss) + 1e-8f);

        // ---- damped update + convergence (identical to r4) ----
        float dd = 0.f;
        #pragma unroll
        for (int i = 0; i < SD; ++i) {
            float un = u[i] * inv;
            float mn = 0.5f * mu[i] + 0.5f * un;
            float d  = mn - mu[i];
            dd = fmaf(d, d, dd);
            mu[i] = mn;
        }
        if (sqrtf(dd) < 1e-4f) conv = 1.0f;
    }

    // lane e<7 stores mu[e]; lane e==7 stores conv (all lanes hold identical mu)
    float val = mu[0];
    val = (e == 1) ? mu[1] : val;
    val = (e == 2) ? mu[2] : val;
    val = (e == 3) ? mu[3] : val;
    val = (e == 4) ? mu[4] : val;
    val = (e == 5) ? mu[5] : val;
    val = (e == 6) ? mu[6] : val;
    if (e < SD) out_mu[(size_t)row * SD + e] = val;
    else        out_cv[row] = conv;
}

extern "C" void kernel_launch(void* const* d_in, const int* in_sizes, int n_in,
                              void* d_out, int out_size, void* d_ws, size_t ws_size,
                              hipStream_t stream) {
    const float* s7  = (const float*)d_in[0];
    const float* w0  = (const float*)d_in[1];
    const float* b0  = (const float*)d_in[2];
    const float* lns = (const float*)d_in[3];
    const float* lnb = (const float*)d_in[4];
    const float* ow  = (const float*)d_in[5];
    const float* ob  = (const float*)d_in[6];
    const int Bn = in_sizes[0] / SD;

    float* out_mu = (float*)d_out;
    float* out_cv = out_mu + (size_t)Bn * SD;

    // 8 lanes per row -> 32 rows per 256-thread block
    const int block = 256;
    const int grid  = (Bn + 31) / 32;
    hipLaunchKernelGGL(strange_loop_kernel, dim3(grid), dim3(block), 0, stream,
                       s7, w0, b0, lns, lnb, ow, ob, out_mu, out_cv, Bn);
}